// Round 2
// baseline (384.189 us; speedup 1.0000x reference)
//
#include <hip/hip_runtime.h>
#include <hip/hip_bf16.h>

#define NRBF 20
#define KAUG 24   // 20 rbf + env(bias row) + 3 zero pad, stored f16

typedef __attribute__((ext_vector_type(8))) short short8;
typedef __attribute__((ext_vector_type(4))) float float4v;
typedef __attribute__((ext_vector_type(2))) _Float16 half2v;
typedef unsigned short ushort_t;

__device__ __forceinline__ float bf2f(ushort_t u) {
    return __uint_as_float(((unsigned)u) << 16);
}
__device__ __forceinline__ ushort_t f2bf(float f) {
    unsigned u = __float_as_uint(f);
    u += 0x7FFF + ((u >> 16) & 1);   // round-to-nearest-even
    return (ushort_t)(u >> 16);
}
__device__ __forceinline__ float ldin(const void* p, size_t idx, int isbf) {
    return isbf ? bf2f(((const ushort_t*)p)[idx]) : ((const float*)p)[idx];
}
__device__ __forceinline__ void stout(void* p, size_t idx, float v, int isbf) {
    if (isbf) ((ushort_t*)p)[idx] = f2bf(v);
    else      ((float*)p)[idx] = v;
}
__device__ __forceinline__ float dot2(half2v a, half2v b, float c) {
#if __has_builtin(__builtin_amdgcn_fdot2)
    return __builtin_amdgcn_fdot2(a, b, c, false);
#else
    return c + (float)a.x * (float)b.x + (float)a.y * (float)b.y;
#endif
}

// ---------------- dtype detect + deg zero (fused) ----------------
__global__ void detect_kernel(const void* __restrict__ xyz, int* __restrict__ flag,
                              int* __restrict__ deg, int N) {
    int idx = blockIdx.x * blockDim.x + threadIdx.x;
    if (idx < N) deg[idx] = 0;
    if (blockIdx.x == 0 && threadIdx.x < 64) {
        const ushort_t* u = (const ushort_t*)xyz;
        unsigned e0 = (u[2 * threadIdx.x] >> 7) & 0xFF;
        unsigned long long bad = __ballot(e0 >= 0x90);
        if (threadIdx.x == 0) *flag = (__popcll(bad) > 2) ? 0 : 1;  // 1=bf16, 0=f32
    }
}

// ---------------- prelude: deg count + s init + weight prep ----------------
// B1 frags [l][ks4][nt8][lane64][8]; B2 frags [l][ks4][nt24][lane64][8];
// WrT f16 [l][col384][KAUG]: k<20 = Wr[l][k][col], k==20 = br[l][col], else 0.
__global__ void prelude_kernel(const void* __restrict__ xyz, const int* __restrict__ nbr,
                               const void* __restrict__ cg_s,
                               const void* __restrict__ W1, const void* __restrict__ W2,
                               const void* __restrict__ Wr, const void* __restrict__ br,
                               float* __restrict__ s_acc, ushort_t* __restrict__ s_hi,
                               ushort_t* __restrict__ s_lo, int* __restrict__ deg,
                               ushort_t* __restrict__ B1hi, ushort_t* __restrict__ B1lo,
                               ushort_t* __restrict__ B2hi, ushort_t* __restrict__ B2lo,
                               _Float16* __restrict__ WrT,
                               int N128, int E, const int* __restrict__ flagp) {
    int isbf = *flagp;
    int idx = blockIdx.x * blockDim.x + threadIdx.x;
    if (idx < E) {
        int i = nbr[2 * idx], j = nbr[2 * idx + 1];
        float dx = ldin(xyz, 3 * j,     isbf) - ldin(xyz, 3 * i,     isbf);
        float dy = ldin(xyz, 3 * j + 1, isbf) - ldin(xyz, 3 * i + 1, isbf);
        float dz = ldin(xyz, 3 * j + 2, isbf) - ldin(xyz, 3 * i + 2, isbf);
        float dist = sqrtf(dx * dx + dy * dy + dz * dz + 3e-15f);
        if (dist < 5.0f) atomicAdd(&deg[i], 1);
    }
    if (idx < N128) {
        float v = ldin(cg_s, idx, isbf);
        s_acc[idx] = v;
        ushort_t hi = f2bf(v);
        s_hi[idx] = hi;
        s_lo[idx] = f2bf(v - bf2f(hi));
    }
    const int NW1 = 3 * 4 * 8 * 64;
    const int NW2 = 3 * 4 * 24 * 64;
    const int NWT = 3 * 384;
    if (idx < NW1) {
        int lane = idx & 63;
        int t = idx >> 6;
        int nt = t % 8; t /= 8;
        int ks = t % 4; int l = t / 4;
        int n = lane & 15, quad = lane >> 4;
        int col = nt * 16 + n;
        size_t base = (size_t)l * 128 * 128;
        size_t fo = (size_t)idx * 8;
        #pragma unroll
        for (int j = 0; j < 8; j++) {
            int k = ks * 32 + quad * 8 + j;
            float v = ldin(W1, base + (size_t)k * 128 + col, isbf);
            ushort_t hi = f2bf(v);
            B1hi[fo + j] = hi;
            B1lo[fo + j] = f2bf(v - bf2f(hi));
        }
    } else if (idx < NW1 + NW2) {
        int i2 = idx - NW1;
        int lane = i2 & 63;
        int t = i2 >> 6;
        int nt = t % 24; t /= 24;
        int ks = t % 4; int l = t / 4;
        int n = lane & 15, quad = lane >> 4;
        int col = nt * 16 + n;
        size_t base = (size_t)l * 128 * 384;
        size_t fo = (size_t)i2 * 8;
        #pragma unroll
        for (int j = 0; j < 8; j++) {
            int k = ks * 32 + quad * 8 + j;
            float v = ldin(W2, base + (size_t)k * 384 + col, isbf);
            ushort_t hi = f2bf(v);
            B2hi[fo + j] = hi;
            B2lo[fo + j] = f2bf(v - bf2f(hi));
        }
    } else if (idx < NW1 + NW2 + NWT) {
        int i2 = idx - NW1 - NW2;
        int l = i2 / 384, col = i2 % 384;
        _Float16* wt = WrT + ((size_t)l * 384 + col) * KAUG;
        #pragma unroll
        for (int k = 0; k < KAUG; k++) {
            float v = 0.f;
            if (k < NRBF) v = ldin(Wr, ((size_t)l * NRBF + k) * 384 + col, isbf);
            else if (k == NRBF) v = ldin(br, (size_t)l * 384 + col, isbf);
            wt[k] = (_Float16)v;
        }
    }
}

// ---------------- scan: rowptr from deg; deg becomes cursor ----------------
__global__ void scan_kernel(int* __restrict__ deg, int* __restrict__ rowptr, int N) {
    __shared__ int part[256];
    int t = threadIdx.x;
    int chunk = (N + 255) / 256;
    int lo = t * chunk, hi = min(lo + chunk, N);
    int s = 0;
    for (int i = lo; i < hi; i++) s += deg[i];
    part[t] = s;
    __syncthreads();
    for (int off = 1; off < 256; off <<= 1) {
        int v = (t >= off) ? part[t - off] : 0;
        __syncthreads();
        if (t >= off) part[t] += v;
        __syncthreads();
    }
    int base = (t == 0) ? 0 : part[t - 1];
    for (int i = lo; i < hi; i++) {
        rowptr[i] = base;
        int d = deg[i];
        deg[i] = base;
        base += d;
    }
    if (t == 0) rowptr[N] = part[255];
}

// ---------------- pack: geometry + CSR scatter (pos-ordered) ----------------
// jlist[pos]=j, upos[pos]=(ux,uy,uz,env), rbfh f16 [pos][KAUG]: k<20 = env*rbf_k,
// k==20 = env (bias row), k>20 = 0.
__global__ void pack_kernel(const void* __restrict__ xyz, const int* __restrict__ nbr,
                            int* __restrict__ cursor, int* __restrict__ jlist,
                            float4* __restrict__ upos, _Float16* __restrict__ rbfh,
                            int E, const int* __restrict__ flagp) {
    int isbf = *flagp;
    int e = blockIdx.x * blockDim.x + threadIdx.x;
    if (e >= E) return;
    int i = nbr[2 * e], j = nbr[2 * e + 1];
    float dx = ldin(xyz, 3 * j,     isbf) - ldin(xyz, 3 * i,     isbf);
    float dy = ldin(xyz, 3 * j + 1, isbf) - ldin(xyz, 3 * i + 1, isbf);
    float dz = ldin(xyz, 3 * j + 2, isbf) - ldin(xyz, 3 * i + 2, isbf);
    float dist = sqrtf(dx * dx + dy * dy + dz * dz + 3e-15f);
    if (!(dist < 5.0f)) return;
    constexpr float PI = 3.14159265358979323846f;
    float ev = 0.5f * (cosf(PI * dist * 0.2f) + 1.0f);
    int pos = atomicAdd(&cursor[i], 1);
    jlist[pos] = j;
    float inv = 1.0f / dist;
    upos[pos] = make_float4(dx * inv, dy * inv, dz * inv, ev);
    constexpr double EM5 = 0.006737946999085467;  // exp(-5)
    constexpr float MU0 = (float)EM5;
    constexpr float DMU = (float)((1.0 - EM5) / 19.0);
    constexpr float BETA = (float)(1.0 / ((0.1 * (1.0 - EM5)) * (0.1 * (1.0 - EM5))));
    float ed = expf(-dist);
    _Float16* rp = rbfh + (size_t)pos * KAUG;
    #pragma unroll
    for (int k = 0; k < NRBF; k++) {
        float dmu = ed - (MU0 + k * DMU);
        rp[k] = (_Float16)(ev * expf(-BETA * dmu * dmu));
    }
    rp[NRBF] = (_Float16)ev;
    #pragma unroll
    for (int k = NRBF + 1; k < KAUG; k++) rp[k] = (_Float16)0.f;
}

// ---------------- fused MFMA GEMM12: phi = silu(s@W1+b1)@W2 + b2 ----------------
// Block = 64 rows (4 waves x 16) x (384/CSPLIT) phi cols. Each wave computes its
// own 16x128 h tile (all 8 col tiles, bias+silu, hi/lo bf16 split), transposes it
// wave-locally through a 32KB XOR-swizzled LDS tile, then consumes it as the MFMA
// A operand for 24/CSPLIT phi col tiles.
// R1 fix (occupancy was 22%, latency-bound at 43us): CSPLIT=8 -> grid gx*8 = 1256
// blocks ~= 4.9 blocks/CU == the 32KB-LDS cap (5/CU), whole grid co-resident at
// ~20 waves/CU. Stage-1 recompute x8 is ~2.5us of 5%-utilized MFMA pipe: free.
// Also: NO __syncthreads — the 4 waves use disjoint per-wave LDS tiles; the
// compiler's conservative lgkmcnt on ds_write->ds_read keeps intra-wave order.
// Swizzle: ushort index col ^= (row&7)<<3  == byte ^= (row&7)<<4; keeps the
// 8-ushort A-frag contiguous (col0 multiple of 8) and makes the row-stride-256B
// ds_read_b128 conflict-free instead of 16-way.
template <int CSPLIT>
__global__ __launch_bounds__(256) void mfma_gemm12(
    const ushort_t* __restrict__ Ahi, const ushort_t* __restrict__ Alo,
    const ushort_t* __restrict__ B1h, const ushort_t* __restrict__ B1l,
    const ushort_t* __restrict__ B2h, const ushort_t* __restrict__ B2l,
    const void* __restrict__ bias1, size_t b1off,
    const void* __restrict__ bias2, size_t b2off,
    ushort_t* __restrict__ phi, int M, const int* __restrict__ flagp) {
    constexpr int T2 = 24 / CSPLIT;      // phi col tiles per block
    int isbf = *flagp;
    int cs = blockIdx.x % CSPLIT;
    int bx = blockIdx.x / CSPLIT;
    int tid = threadIdx.x;
    int wave = tid >> 6, lane = tid & 63;
    int m = lane & 15, quad = lane >> 4;
    int brow = bx * 64 + wave * 16;
    int row = brow + m;

    __shared__ ushort_t Hhi[4][16 * 128];
    __shared__ ushort_t Hlo[4][16 * 128];

    short8 zero8 = {};
    // hoist this wave's A fragments (s rows, 4 k-slices)
    short8 ah[4], al[4];
    #pragma unroll
    for (int ks = 0; ks < 4; ks++) {
        ah[ks] = zero8; al[ks] = zero8;
        if (row < M) {
            size_t ao = (size_t)row * 128 + ks * 32 + quad * 8;
            ah[ks] = *reinterpret_cast<const short8*>(Ahi + ao);
            al[ks] = *reinterpret_cast<const short8*>(Alo + ao);
        }
    }
    // ---- stage 1: h = silu(s @ W1 + b1), full 16x128 per wave ----
    #pragma unroll
    for (int ct = 0; ct < 8; ct++) {
        float4v acc = {};
        #pragma unroll
        for (int ks = 0; ks < 4; ks++) {
            size_t fo = (((size_t)ks * 8 + ct) * 64 + lane) * 8;
            short8 bh = *reinterpret_cast<const short8*>(B1h + fo);
            acc = __builtin_amdgcn_mfma_f32_16x16x32_bf16(ah[ks], bh, acc, 0, 0, 0);
            acc = __builtin_amdgcn_mfma_f32_16x16x32_bf16(al[ks], bh, acc, 0, 0, 0);
            if (!isbf) {
                short8 bl = *reinterpret_cast<const short8*>(B1l + fo);
                acc = __builtin_amdgcn_mfma_f32_16x16x32_bf16(ah[ks], bl, acc, 0, 0, 0);
            }
        }
        int col = ct * 16 + m;
        float bv = ldin(bias1, b1off + col, isbf);
        #pragma unroll
        for (int r = 0; r < 4; r++) {
            int hrow = quad * 4 + r;          // C layout: row = quad*4 + r
            float x = acc[r] + bv;
            x = x / (1.0f + expf(-x));        // silu
            ushort_t hi = f2bf(x);
            int ci = col ^ ((hrow & 7) << 3); // XOR swizzle
            Hhi[wave][hrow * 128 + ci] = hi;
            Hlo[wave][hrow * 128 + ci] = f2bf(x - bf2f(hi));
        }
    }
    // no __syncthreads(): waves use disjoint LDS tiles; compiler emits the
    // intra-wave lgkmcnt ordering for the ds_write -> ds_read dependency.
    // ---- stage 2: phi = h @ W2 + b2 for this block's T2 col tiles ----
    #pragma unroll
    for (int t = 0; t < T2; t++) {
        int nt = cs * T2 + t;
        float4v acc = {};
        #pragma unroll
        for (int ks = 0; ks < 4; ks++) {
            int c0 = (ks * 32 + quad * 8) ^ ((m & 7) << 3);
            short8 hh = *reinterpret_cast<const short8*>(&Hhi[wave][m * 128 + c0]);
            short8 hl = *reinterpret_cast<const short8*>(&Hlo[wave][m * 128 + c0]);
            size_t fo = (((size_t)ks * 24 + nt) * 64 + lane) * 8;
            short8 bh = *reinterpret_cast<const short8*>(B2h + fo);
            acc = __builtin_amdgcn_mfma_f32_16x16x32_bf16(hh, bh, acc, 0, 0, 0);
            acc = __builtin_amdgcn_mfma_f32_16x16x32_bf16(hl, bh, acc, 0, 0, 0);
            if (!isbf) {
                short8 bl = *reinterpret_cast<const short8*>(B2l + fo);
                acc = __builtin_amdgcn_mfma_f32_16x16x32_bf16(hh, bl, acc, 0, 0, 0);
            }
        }
        int col = nt * 16 + m;
        float bv = ldin(bias2, b2off + col, isbf);
        #pragma unroll
        for (int r = 0; r < 4; r++) {
            int orow = brow + quad * 4 + r;
            if (orow >= M) continue;
            float x = acc[r] + bv;
            phi[(size_t)orow * 384 + col] = f2bf(x);
        }
    }
}

// ---------------- node gather kernel (r4/r8 structure + f16 dot2 w-dot) ----------
// One block per node, 128 threads; thread tt owns features {tt, 128+tt, 256+tt}.
// w-dot: 11 half2 pairs (20 rbf + env/bias + zero pad) via v_dot2 -> 33 instr,
// wc registers = 33 half2 (fits VGPR budget, unlike 63 floats).
template <int L0, int LAST>
__global__ __launch_bounds__(128, 8) void node_kernel(
    const int* __restrict__ rowptr, const int* __restrict__ jlist,
    const float4* __restrict__ upos, const _Float16* __restrict__ rbfh,
    const _Float16* __restrict__ WrT,
    const ushort_t* __restrict__ phi,
    const float* __restrict__ v_old, const ushort_t* __restrict__ vh_old,
    float* __restrict__ s_acc, ushort_t* __restrict__ s_hi, ushort_t* __restrict__ s_lo,
    float* __restrict__ v_new, ushort_t* __restrict__ vh_new,
    void* __restrict__ out, int N, const int* __restrict__ flagp) {
    int isbf = *flagp;
    int tt = threadIdx.x;
    int node = blockIdx.x;

    // hoist this thread's 3 WrT columns: 11 half2 each (44B contiguous)
    half2v wc0[11], wc1[11], wc2[11];
    {
        const half2v* w0p = (const half2v*)(WrT + (size_t)tt * KAUG);
        const half2v* w1p = (const half2v*)(WrT + (size_t)(tt + 128) * KAUG);
        const half2v* w2p = (const half2v*)(WrT + (size_t)(tt + 256) * KAUG);
        #pragma unroll
        for (int k = 0; k < 11; k++) {
            wc0[k] = w0p[k]; wc1[k] = w1p[k]; wc2[k] = w2p[k];
        }
    }
    int start = __builtin_amdgcn_readfirstlane(rowptr[node]);
    int end   = __builtin_amdgcn_readfirstlane(rowptr[node + 1]);

    float dsv = 0.f, ax = 0.f, ay = 0.f, az = 0.f;
    for (int k = start; k < end; k++) {
        int j = __builtin_amdgcn_readfirstlane(jlist[k]);
        float4 u4 = upos[k];
        const half2v* rp = (const half2v*)(rbfh + (size_t)k * KAUG);
        float w0 = 0.f, w1 = 0.f, w2 = 0.f;
        #pragma unroll
        for (int r = 0; r < 11; r++) {
            half2v rv = rp[r];
            w0 = dot2(rv, wc0[r], w0);
            w1 = dot2(rv, wc1[r], w1);
            w2 = dot2(rv, wc2[r], w2);
        }
        size_t jb = (size_t)j * 384;
        dsv += bf2f(phi[jb + tt]) * w0;
        float gv = bf2f(phi[jb + 128 + tt]) * w1;
        float gu = bf2f(phi[jb + 256 + tt]) * w2;
        if (L0) {
            ax += gu * u4.x; ay += gu * u4.y; az += gu * u4.z;
        } else {
            const ushort_t* vj = &vh_old[jb + (size_t)tt * 3];
            ax += gu * u4.x + gv * bf2f(vj[0]);
            ay += gu * u4.y + gv * bf2f(vj[1]);
            az += gu * u4.z + gv * bf2f(vj[2]);
        }
    }
    size_t so = (size_t)node * 128 + tt;
    float snew = s_acc[so] + dsv;
    size_t ib = (size_t)node * 384 + (size_t)tt * 3;
    float vx = L0 ? ax : v_old[ib]     + ax;
    float vy = L0 ? ay : v_old[ib + 1] + ay;
    float vz = L0 ? az : v_old[ib + 2] + az;
    if (LAST) {
        stout(out, so, snew, isbf);
        size_t ob = (size_t)N * 128 + ib;
        stout(out, ob,     vx, isbf);
        stout(out, ob + 1, vy, isbf);
        stout(out, ob + 2, vz, isbf);
    } else {
        s_acc[so] = snew;
        ushort_t hi = f2bf(snew);
        s_hi[so] = hi;
        s_lo[so] = f2bf(snew - bf2f(hi));
        v_new[ib] = vx; v_new[ib + 1] = vy; v_new[ib + 2] = vz;
        vh_new[ib]     = f2bf(vx);
        vh_new[ib + 1] = f2bf(vy);
        vh_new[ib + 2] = f2bf(vz);
    }
}

extern "C" void kernel_launch(void* const* d_in, const int* in_sizes, int n_in,
                              void* d_out, int out_size, void* d_ws, size_t ws_size,
                              hipStream_t stream) {
    const int N = in_sizes[0] / 3;
    const int E = in_sizes[1] / 2;
    const void* xyz  = d_in[0];
    const int*  nbr  = (const int*)d_in[1];
    const void* cg_s = d_in[2];
    const void* W1   = d_in[3];
    const void* b1   = d_in[4];
    const void* W2   = d_in[5];
    const void* b2   = d_in[6];
    const void* Wr   = d_in[7];
    const void* br   = d_in[8];

    size_t off = 0;
    auto alloc = [&](size_t bytes) -> char* {
        char* p = (char*)d_ws + off;
        off = (off + bytes + 63) & ~(size_t)63;
        return p;
    };
    int*       flag   = (int*)alloc(64);
    float*     s_acc  = (float*)alloc((size_t)N * 128 * 4);
    float*     vA     = (float*)alloc((size_t)N * 384 * 4);
    float*     vB     = (float*)alloc((size_t)N * 384 * 4);
    int*       rowptr = (int*)alloc((size_t)(N + 1) * 4);
    int*       deg    = (int*)alloc((size_t)N * 4);
    int*       jlist  = (int*)alloc((size_t)E * 4);
    float4*    upos   = (float4*)alloc((size_t)(E + 16) * 16);
    _Float16*  rbfh   = (_Float16*)alloc((size_t)(E + 16) * KAUG * 2);
    _Float16*  WrT    = (_Float16*)alloc((size_t)3 * 384 * KAUG * 2);
    ushort_t*  s_hi   = (ushort_t*)alloc((size_t)N * 128 * 2);
    ushort_t*  s_lo   = (ushort_t*)alloc((size_t)N * 128 * 2);
    ushort_t*  phi    = (ushort_t*)alloc((size_t)N * 384 * 2);
    ushort_t*  vhA    = (ushort_t*)alloc((size_t)N * 384 * 2);
    ushort_t*  vhB    = (ushort_t*)alloc((size_t)N * 384 * 2);
    ushort_t*  B1hi   = (ushort_t*)alloc((size_t)3 * 4 * 8 * 64 * 8 * 2);
    ushort_t*  B1lo   = (ushort_t*)alloc((size_t)3 * 4 * 8 * 64 * 8 * 2);
    ushort_t*  B2hi   = (ushort_t*)alloc((size_t)3 * 4 * 24 * 64 * 8 * 2);
    ushort_t*  B2lo   = (ushort_t*)alloc((size_t)3 * 4 * 24 * 64 * 8 * 2);

    detect_kernel<<<(N + 255) / 256, 256, 0, stream>>>(xyz, flag, deg, N);
    const int N128 = N * 128;
    const int pg = (max(E, N128) + 255) / 256;
    prelude_kernel<<<pg, 256, 0, stream>>>(xyz, nbr, cg_s, W1, W2, Wr, br,
                                           s_acc, s_hi, s_lo, deg,
                                           B1hi, B1lo, B2hi, B2lo, WrT,
                                           N128, E, flag);
    scan_kernel<<<1, 256, 0, stream>>>(deg, rowptr, N);
    pack_kernel<<<(E + 255) / 256, 256, 0, stream>>>(xyz, nbr, deg, jlist, upos,
                                                     rbfh, E, flag);

    const int gx = (N + 63) / 64;
    for (int l = 0; l < 3; l++) {
        mfma_gemm12<8><<<gx * 8, 256, 0, stream>>>(
            s_hi, s_lo,
            B1hi + (size_t)l * 4 * 8 * 64 * 8,  B1lo + (size_t)l * 4 * 8 * 64 * 8,
            B2hi + (size_t)l * 4 * 24 * 64 * 8, B2lo + (size_t)l * 4 * 24 * 64 * 8,
            b1, (size_t)l * 128, b2, (size_t)l * 384, phi, N, flag);
        const _Float16* wrt = WrT + (size_t)l * 384 * KAUG;
        if (l == 0) {
            node_kernel<1, 0><<<N, 128, 0, stream>>>(
                rowptr, jlist, upos, rbfh, wrt, phi,
                vA, vhA, s_acc, s_hi, s_lo, vA, vhA, d_out, N, flag);
        } else if (l == 1) {
            node_kernel<0, 0><<<N, 128, 0, stream>>>(
                rowptr, jlist, upos, rbfh, wrt, phi,
                vA, vhA, s_acc, s_hi, s_lo, vB, vhB, d_out, N, flag);
        } else {
            node_kernel<0, 1><<<N, 128, 0, stream>>>(
                rowptr, jlist, upos, rbfh, wrt, phi,
                vB, vhB, s_acc, s_hi, s_lo, vB, vhB, d_out, N, flag);
        }
    }
}

// Round 3
// 330.956 us; speedup vs baseline: 1.1608x; 1.1608x over previous
//
#include <hip/hip_runtime.h>
#include <hip/hip_bf16.h>

#define NRBF 20
#define KAUG 24   // 20 rbf + env(bias row) + 3 zero pad, stored f16

typedef __attribute__((ext_vector_type(8))) short short8;
typedef __attribute__((ext_vector_type(4))) float float4v;
typedef __attribute__((ext_vector_type(2))) _Float16 half2v;
typedef unsigned short ushort_t;

__device__ __forceinline__ float bf2f(ushort_t u) {
    return __uint_as_float(((unsigned)u) << 16);
}
__device__ __forceinline__ ushort_t f2bf(float f) {
    unsigned u = __float_as_uint(f);
    u += 0x7FFF + ((u >> 16) & 1);   // round-to-nearest-even
    return (ushort_t)(u >> 16);
}
__device__ __forceinline__ float ldin(const void* p, size_t idx, int isbf) {
    return isbf ? bf2f(((const ushort_t*)p)[idx]) : ((const float*)p)[idx];
}
__device__ __forceinline__ void stout(void* p, size_t idx, float v, int isbf) {
    if (isbf) ((ushort_t*)p)[idx] = f2bf(v);
    else      ((float*)p)[idx] = v;
}
__device__ __forceinline__ float dot2(half2v a, half2v b, float c) {
#if __has_builtin(__builtin_amdgcn_fdot2)
    return __builtin_amdgcn_fdot2(a, b, c, false);
#else
    return c + (float)a.x * (float)b.x + (float)a.y * (float)b.y;
#endif
}

// ---------------- dtype detect + deg zero (fused) ----------------
__global__ void detect_kernel(const void* __restrict__ xyz, int* __restrict__ flag,
                              int* __restrict__ deg, int N) {
    int idx = blockIdx.x * blockDim.x + threadIdx.x;
    if (idx < N) deg[idx] = 0;
    if (blockIdx.x == 0 && threadIdx.x < 64) {
        const ushort_t* u = (const ushort_t*)xyz;
        unsigned e0 = (u[2 * threadIdx.x] >> 7) & 0xFF;
        unsigned long long bad = __ballot(e0 >= 0x90);
        if (threadIdx.x == 0) *flag = (__popcll(bad) > 2) ? 0 : 1;  // 1=bf16, 0=f32
    }
}

// ---------------- prelude: deg count + s init + weight prep ----------------
// B1 frags [l][ks4][nt8][lane64][8]; B2 frags [l][ks4][nt24][lane64][8];
// WrT f16 [l][col384][KAUG]: k<20 = Wr[l][k][col], k==20 = br[l][col], else 0.
__global__ void prelude_kernel(const void* __restrict__ xyz, const int* __restrict__ nbr,
                               const void* __restrict__ cg_s,
                               const void* __restrict__ W1, const void* __restrict__ W2,
                               const void* __restrict__ Wr, const void* __restrict__ br,
                               float* __restrict__ s_acc, ushort_t* __restrict__ s_hi,
                               ushort_t* __restrict__ s_lo, int* __restrict__ deg,
                               ushort_t* __restrict__ B1hi, ushort_t* __restrict__ B1lo,
                               ushort_t* __restrict__ B2hi, ushort_t* __restrict__ B2lo,
                               _Float16* __restrict__ WrT,
                               int N128, int E, const int* __restrict__ flagp) {
    int isbf = *flagp;
    int idx = blockIdx.x * blockDim.x + threadIdx.x;
    if (idx < E) {
        int i = nbr[2 * idx], j = nbr[2 * idx + 1];
        float dx = ldin(xyz, 3 * j,     isbf) - ldin(xyz, 3 * i,     isbf);
        float dy = ldin(xyz, 3 * j + 1, isbf) - ldin(xyz, 3 * i + 1, isbf);
        float dz = ldin(xyz, 3 * j + 2, isbf) - ldin(xyz, 3 * i + 2, isbf);
        float dist = sqrtf(dx * dx + dy * dy + dz * dz + 3e-15f);
        if (dist < 5.0f) atomicAdd(&deg[i], 1);
    }
    if (idx < N128) {
        float v = ldin(cg_s, idx, isbf);
        s_acc[idx] = v;
        ushort_t hi = f2bf(v);
        s_hi[idx] = hi;
        s_lo[idx] = f2bf(v - bf2f(hi));
    }
    const int NW1 = 3 * 4 * 8 * 64;
    const int NW2 = 3 * 4 * 24 * 64;
    const int NWT = 3 * 384;
    if (idx < NW1) {
        int lane = idx & 63;
        int t = idx >> 6;
        int nt = t % 8; t /= 8;
        int ks = t % 4; int l = t / 4;
        int n = lane & 15, quad = lane >> 4;
        int col = nt * 16 + n;
        size_t base = (size_t)l * 128 * 128;
        size_t fo = (size_t)idx * 8;
        #pragma unroll
        for (int j = 0; j < 8; j++) {
            int k = ks * 32 + quad * 8 + j;
            float v = ldin(W1, base + (size_t)k * 128 + col, isbf);
            ushort_t hi = f2bf(v);
            B1hi[fo + j] = hi;
            B1lo[fo + j] = f2bf(v - bf2f(hi));
        }
    } else if (idx < NW1 + NW2) {
        int i2 = idx - NW1;
        int lane = i2 & 63;
        int t = i2 >> 6;
        int nt = t % 24; t /= 24;
        int ks = t % 4; int l = t / 4;
        int n = lane & 15, quad = lane >> 4;
        int col = nt * 16 + n;
        size_t base = (size_t)l * 128 * 384;
        size_t fo = (size_t)i2 * 8;
        #pragma unroll
        for (int j = 0; j < 8; j++) {
            int k = ks * 32 + quad * 8 + j;
            float v = ldin(W2, base + (size_t)k * 384 + col, isbf);
            ushort_t hi = f2bf(v);
            B2hi[fo + j] = hi;
            B2lo[fo + j] = f2bf(v - bf2f(hi));
        }
    } else if (idx < NW1 + NW2 + NWT) {
        int i2 = idx - NW1 - NW2;
        int l = i2 / 384, col = i2 % 384;
        _Float16* wt = WrT + ((size_t)l * 384 + col) * KAUG;
        #pragma unroll
        for (int k = 0; k < KAUG; k++) {
            float v = 0.f;
            if (k < NRBF) v = ldin(Wr, ((size_t)l * NRBF + k) * 384 + col, isbf);
            else if (k == NRBF) v = ldin(br, (size_t)l * 384 + col, isbf);
            wt[k] = (_Float16)v;
        }
    }
}

// ---------------- scan: rowptr from deg; deg becomes cursor ----------------
__global__ void scan_kernel(int* __restrict__ deg, int* __restrict__ rowptr, int N) {
    __shared__ int part[256];
    int t = threadIdx.x;
    int chunk = (N + 255) / 256;
    int lo = t * chunk, hi = min(lo + chunk, N);
    int s = 0;
    for (int i = lo; i < hi; i++) s += deg[i];
    part[t] = s;
    __syncthreads();
    for (int off = 1; off < 256; off <<= 1) {
        int v = (t >= off) ? part[t - off] : 0;
        __syncthreads();
        if (t >= off) part[t] += v;
        __syncthreads();
    }
    int base = (t == 0) ? 0 : part[t - 1];
    for (int i = lo; i < hi; i++) {
        rowptr[i] = base;
        int d = deg[i];
        deg[i] = base;
        base += d;
    }
    if (t == 0) rowptr[N] = part[255];
}

// ---------------- pack: geometry + CSR scatter (pos-ordered) ----------------
// jlist[pos]=j, upos[pos]=(ux,uy,uz,env), rbfh f16 [pos][KAUG]: k<20 = env*rbf_k,
// k==20 = env (bias row), k>20 = 0.
__global__ void pack_kernel(const void* __restrict__ xyz, const int* __restrict__ nbr,
                            int* __restrict__ cursor, int* __restrict__ jlist,
                            float4* __restrict__ upos, _Float16* __restrict__ rbfh,
                            int E, const int* __restrict__ flagp) {
    int isbf = *flagp;
    int e = blockIdx.x * blockDim.x + threadIdx.x;
    if (e >= E) return;
    int i = nbr[2 * e], j = nbr[2 * e + 1];
    float dx = ldin(xyz, 3 * j,     isbf) - ldin(xyz, 3 * i,     isbf);
    float dy = ldin(xyz, 3 * j + 1, isbf) - ldin(xyz, 3 * i + 1, isbf);
    float dz = ldin(xyz, 3 * j + 2, isbf) - ldin(xyz, 3 * i + 2, isbf);
    float dist = sqrtf(dx * dx + dy * dy + dz * dz + 3e-15f);
    if (!(dist < 5.0f)) return;
    constexpr float PI = 3.14159265358979323846f;
    float ev = 0.5f * (cosf(PI * dist * 0.2f) + 1.0f);
    int pos = atomicAdd(&cursor[i], 1);
    jlist[pos] = j;
    float inv = 1.0f / dist;
    upos[pos] = make_float4(dx * inv, dy * inv, dz * inv, ev);
    constexpr double EM5 = 0.006737946999085467;  // exp(-5)
    constexpr float MU0 = (float)EM5;
    constexpr float DMU = (float)((1.0 - EM5) / 19.0);
    constexpr float BETA = (float)(1.0 / ((0.1 * (1.0 - EM5)) * (0.1 * (1.0 - EM5))));
    float ed = expf(-dist);
    _Float16* rp = rbfh + (size_t)pos * KAUG;
    #pragma unroll
    for (int k = 0; k < NRBF; k++) {
        float dmu = ed - (MU0 + k * DMU);
        rp[k] = (_Float16)(ev * expf(-BETA * dmu * dmu));
    }
    rp[NRBF] = (_Float16)ev;
    #pragma unroll
    for (int k = NRBF + 1; k < KAUG; k++) rp[k] = (_Float16)0.f;
}

// ---------------- MFMA GEMM, 1D swizzled grid for A-locality ----------------
// grid = ceil(M/64) * NTILES, 1D: nt = idx % NTILES (fast), bx = idx / NTILES
// -> consecutive blocks share the same 64 A-rows (L1/L2-hot); B frags are small.
template <int ACT, int OUTMODE, int NTILES>
__global__ __launch_bounds__(256) void mfma_gemm(
    const ushort_t* __restrict__ Ahi, const ushort_t* __restrict__ Alo,
    const ushort_t* __restrict__ Bhi, const ushort_t* __restrict__ Blo,
    const void* __restrict__ bias, size_t biasoff,
    ushort_t* __restrict__ out_hi, ushort_t* __restrict__ out_lo,
    int M, const int* __restrict__ flagp) {
    constexpr int Ncols = NTILES * 16;
    int isbf = *flagp;
    int nt = blockIdx.x % NTILES;
    int bx = blockIdx.x / NTILES;
    int tid = threadIdx.x;
    int wave = tid >> 6, lane = tid & 63;
    int m = lane & 15, quad = lane >> 4;
    int brow = bx * 64 + wave * 16;
    int row = brow + m;
    float4v acc = {};
    short8 zero8 = {};
    #pragma unroll
    for (int ks = 0; ks < 4; ks++) {
        short8 ah = zero8, al = zero8;
        if (row < M) {
            size_t ao = (size_t)row * 128 + ks * 32 + quad * 8;
            ah = *reinterpret_cast<const short8*>(Ahi + ao);
            al = *reinterpret_cast<const short8*>(Alo + ao);
        }
        size_t fo = (((size_t)ks * NTILES + nt) * 64 + lane) * 8;
        short8 bh = *reinterpret_cast<const short8*>(Bhi + fo);
        acc = __builtin_amdgcn_mfma_f32_16x16x32_bf16(ah, bh, acc, 0, 0, 0);
        acc = __builtin_amdgcn_mfma_f32_16x16x32_bf16(al, bh, acc, 0, 0, 0);
        if (!isbf) {
            short8 bl = *reinterpret_cast<const short8*>(Blo + fo);
            acc = __builtin_amdgcn_mfma_f32_16x16x32_bf16(ah, bl, acc, 0, 0, 0);
        }
    }
    int col = nt * 16 + m;
    float bv = ldin(bias, biasoff + col, isbf);
    #pragma unroll
    for (int r = 0; r < 4; r++) {
        int orow = brow + quad * 4 + r;
        if (orow >= M) continue;
        float x = acc[r] + bv;
        if (ACT) x = x / (1.0f + expf(-x));  // silu
        size_t oo = (size_t)orow * Ncols + col;
        ushort_t h = f2bf(x);
        out_hi[oo] = h;
        if (OUTMODE == 0) out_lo[oo] = f2bf(x - bf2f(h));
    }
}

// ---------------- node gather kernel (r4/r8 structure + f16 dot2 w-dot) ----------
// One block per node, 128 threads; thread tt owns features {tt, 128+tt, 256+tt}.
// w-dot: 11 half2 pairs (20 rbf + env/bias + zero pad) via v_dot2 -> 33 instr,
// wc registers = 33 half2 (fits VGPR budget, unlike 63 floats).
// R3: scalar j-prefetch pipeline — jlist[k+1] (SGPR via readfirstlane, zero VGPR
// cost) is loaded at the top of iteration k, breaking the cross-iteration
// j-load -> phi-gather serial dependency; per-iter exposed latency drops from
// (j_lat + gather_lat) to ~gather_lat.
template <int L0, int LAST>
__global__ __launch_bounds__(128, 8) void node_kernel(
    const int* __restrict__ rowptr, const int* __restrict__ jlist,
    const float4* __restrict__ upos, const _Float16* __restrict__ rbfh,
    const _Float16* __restrict__ WrT,
    const ushort_t* __restrict__ phi,
    const float* __restrict__ v_old, const ushort_t* __restrict__ vh_old,
    float* __restrict__ s_acc, ushort_t* __restrict__ s_hi, ushort_t* __restrict__ s_lo,
    float* __restrict__ v_new, ushort_t* __restrict__ vh_new,
    void* __restrict__ out, int N, const int* __restrict__ flagp) {
    int isbf = *flagp;
    int tt = threadIdx.x;
    int node = blockIdx.x;

    // hoist this thread's 3 WrT columns: 11 half2 each (44B contiguous)
    half2v wc0[11], wc1[11], wc2[11];
    {
        const half2v* w0p = (const half2v*)(WrT + (size_t)tt * KAUG);
        const half2v* w1p = (const half2v*)(WrT + (size_t)(tt + 128) * KAUG);
        const half2v* w2p = (const half2v*)(WrT + (size_t)(tt + 256) * KAUG);
        #pragma unroll
        for (int k = 0; k < 11; k++) {
            wc0[k] = w0p[k]; wc1[k] = w1p[k]; wc2[k] = w2p[k];
        }
    }
    int start = __builtin_amdgcn_readfirstlane(rowptr[node]);
    int end   = __builtin_amdgcn_readfirstlane(rowptr[node + 1]);

    float dsv = 0.f, ax = 0.f, ay = 0.f, az = 0.f;
    // scalar j prefetch: j for edge k is loaded during iteration k-1
    int j = (start < end) ? __builtin_amdgcn_readfirstlane(jlist[start]) : 0;
    for (int k = start; k < end; k++) {
        int jn = j;
        if (k + 1 < end) jn = __builtin_amdgcn_readfirstlane(jlist[k + 1]);
        float4 u4 = upos[k];
        const half2v* rp = (const half2v*)(rbfh + (size_t)k * KAUG);
        float w0 = 0.f, w1 = 0.f, w2 = 0.f;
        #pragma unroll
        for (int r = 0; r < 11; r++) {
            half2v rv = rp[r];
            w0 = dot2(rv, wc0[r], w0);
            w1 = dot2(rv, wc1[r], w1);
            w2 = dot2(rv, wc2[r], w2);
        }
        size_t jb = (size_t)j * 384;
        dsv += bf2f(phi[jb + tt]) * w0;
        float gv = bf2f(phi[jb + 128 + tt]) * w1;
        float gu = bf2f(phi[jb + 256 + tt]) * w2;
        if (L0) {
            ax += gu * u4.x; ay += gu * u4.y; az += gu * u4.z;
        } else {
            const ushort_t* vj = &vh_old[jb + (size_t)tt * 3];
            ax += gu * u4.x + gv * bf2f(vj[0]);
            ay += gu * u4.y + gv * bf2f(vj[1]);
            az += gu * u4.z + gv * bf2f(vj[2]);
        }
        j = jn;
    }
    size_t so = (size_t)node * 128 + tt;
    float snew = s_acc[so] + dsv;
    size_t ib = (size_t)node * 384 + (size_t)tt * 3;
    float vx = L0 ? ax : v_old[ib]     + ax;
    float vy = L0 ? ay : v_old[ib + 1] + ay;
    float vz = L0 ? az : v_old[ib + 2] + az;
    if (LAST) {
        stout(out, so, snew, isbf);
        size_t ob = (size_t)N * 128 + ib;
        stout(out, ob,     vx, isbf);
        stout(out, ob + 1, vy, isbf);
        stout(out, ob + 2, vz, isbf);
    } else {
        s_acc[so] = snew;
        ushort_t hi = f2bf(snew);
        s_hi[so] = hi;
        s_lo[so] = f2bf(snew - bf2f(hi));
        v_new[ib] = vx; v_new[ib + 1] = vy; v_new[ib + 2] = vz;
        vh_new[ib]     = f2bf(vx);
        vh_new[ib + 1] = f2bf(vy);
        vh_new[ib + 2] = f2bf(vz);
    }
}

extern "C" void kernel_launch(void* const* d_in, const int* in_sizes, int n_in,
                              void* d_out, int out_size, void* d_ws, size_t ws_size,
                              hipStream_t stream) {
    const int N = in_sizes[0] / 3;
    const int E = in_sizes[1] / 2;
    const void* xyz  = d_in[0];
    const int*  nbr  = (const int*)d_in[1];
    const void* cg_s = d_in[2];
    const void* W1   = d_in[3];
    const void* b1   = d_in[4];
    const void* W2   = d_in[5];
    const void* b2   = d_in[6];
    const void* Wr   = d_in[7];
    const void* br   = d_in[8];

    size_t off = 0;
    auto alloc = [&](size_t bytes) -> char* {
        char* p = (char*)d_ws + off;
        off = (off + bytes + 63) & ~(size_t)63;
        return p;
    };
    int*       flag   = (int*)alloc(64);
    float*     s_acc  = (float*)alloc((size_t)N * 128 * 4);
    float*     vA     = (float*)alloc((size_t)N * 384 * 4);
    float*     vB     = (float*)alloc((size_t)N * 384 * 4);
    int*       rowptr = (int*)alloc((size_t)(N + 1) * 4);
    int*       deg    = (int*)alloc((size_t)N * 4);
    int*       jlist  = (int*)alloc((size_t)E * 4);
    float4*    upos   = (float4*)alloc((size_t)(E + 16) * 16);
    _Float16*  rbfh   = (_Float16*)alloc((size_t)(E + 16) * KAUG * 2);
    _Float16*  WrT    = (_Float16*)alloc((size_t)3 * 384 * KAUG * 2);
    ushort_t*  s_hi   = (ushort_t*)alloc((size_t)N * 128 * 2);
    ushort_t*  s_lo   = (ushort_t*)alloc((size_t)N * 128 * 2);
    ushort_t*  h_hi   = (ushort_t*)alloc((size_t)N * 128 * 2);
    ushort_t*  h_lo   = (ushort_t*)alloc((size_t)N * 128 * 2);
    ushort_t*  phi    = (ushort_t*)alloc((size_t)N * 384 * 2);
    ushort_t*  vhA    = (ushort_t*)alloc((size_t)N * 384 * 2);
    ushort_t*  vhB    = (ushort_t*)alloc((size_t)N * 384 * 2);
    ushort_t*  B1hi   = (ushort_t*)alloc((size_t)3 * 4 * 8 * 64 * 8 * 2);
    ushort_t*  B1lo   = (ushort_t*)alloc((size_t)3 * 4 * 8 * 64 * 8 * 2);
    ushort_t*  B2hi   = (ushort_t*)alloc((size_t)3 * 4 * 24 * 64 * 8 * 2);
    ushort_t*  B2lo   = (ushort_t*)alloc((size_t)3 * 4 * 24 * 64 * 8 * 2);

    detect_kernel<<<(N + 255) / 256, 256, 0, stream>>>(xyz, flag, deg, N);
    const int N128 = N * 128;
    const int pg = (max(E, N128) + 255) / 256;
    prelude_kernel<<<pg, 256, 0, stream>>>(xyz, nbr, cg_s, W1, W2, Wr, br,
                                           s_acc, s_hi, s_lo, deg,
                                           B1hi, B1lo, B2hi, B2lo, WrT,
                                           N128, E, flag);
    scan_kernel<<<1, 256, 0, stream>>>(deg, rowptr, N);
    pack_kernel<<<(E + 255) / 256, 256, 0, stream>>>(xyz, nbr, deg, jlist, upos,
                                                     rbfh, E, flag);

    const int gx = (N + 63) / 64;
    for (int l = 0; l < 3; l++) {
        mfma_gemm<1, 0, 8><<<gx * 8, 256, 0, stream>>>(
            s_hi, s_lo,
            B1hi + (size_t)l * 4 * 8 * 64 * 8, B1lo + (size_t)l * 4 * 8 * 64 * 8,
            b1, (size_t)l * 128, h_hi, h_lo, N, flag);
        mfma_gemm<0, 1, 24><<<gx * 24, 256, 0, stream>>>(
            h_hi, h_lo,
            B2hi + (size_t)l * 4 * 24 * 64 * 8, B2lo + (size_t)l * 4 * 24 * 64 * 8,
            b2, (size_t)l * 384, phi, (ushort_t*)nullptr, N, flag);
        const _Float16* wrt = WrT + (size_t)l * 384 * KAUG;
        if (l == 0) {
            node_kernel<1, 0><<<N, 128, 0, stream>>>(
                rowptr, jlist, upos, rbfh, wrt, phi,
                vA, vhA, s_acc, s_hi, s_lo, vA, vhA, d_out, N, flag);
        } else if (l == 1) {
            node_kernel<0, 0><<<N, 128, 0, stream>>>(
                rowptr, jlist, upos, rbfh, wrt, phi,
                vA, vhA, s_acc, s_hi, s_lo, vB, vhB, d_out, N, flag);
        } else {
            node_kernel<0, 1><<<N, 128, 0, stream>>>(
                rowptr, jlist, upos, rbfh, wrt, phi,
                vB, vhB, s_acc, s_hi, s_lo, vB, vhB, d_out, N, flag);
        }
    }
}

// Round 4
// 329.935 us; speedup vs baseline: 1.1644x; 1.0031x over previous
//
#include <hip/hip_runtime.h>
#include <hip/hip_bf16.h>

#define NRBF 20
#define KAUG 24   // 20 rbf + env(bias row) + 3 zero pad, stored f16

typedef __attribute__((ext_vector_type(8))) short short8;
typedef __attribute__((ext_vector_type(4))) float float4v;
typedef __attribute__((ext_vector_type(2))) _Float16 half2v;
typedef unsigned short ushort_t;

__device__ __forceinline__ float bf2f(ushort_t u) {
    return __uint_as_float(((unsigned)u) << 16);
}
__device__ __forceinline__ ushort_t f2bf(float f) {
    unsigned u = __float_as_uint(f);
    u += 0x7FFF + ((u >> 16) & 1);   // round-to-nearest-even
    return (ushort_t)(u >> 16);
}
__device__ __forceinline__ float ldin(const void* p, size_t idx, int isbf) {
    return isbf ? bf2f(((const ushort_t*)p)[idx]) : ((const float*)p)[idx];
}
__device__ __forceinline__ void stout(void* p, size_t idx, float v, int isbf) {
    if (isbf) ((ushort_t*)p)[idx] = f2bf(v);
    else      ((float*)p)[idx] = v;
}
__device__ __forceinline__ float dot2(half2v a, half2v b, float c) {
#if __has_builtin(__builtin_amdgcn_fdot2)
    return __builtin_amdgcn_fdot2(a, b, c, false);
#else
    return c + (float)a.x * (float)b.x + (float)a.y * (float)b.y;
#endif
}

// view a 16B float4 register quad as 4 half2 lanes (free re-alias, no moves)
union F4H {
    float4v f;
    half2v  h[4];
};

// ---------------- dtype detect + deg zero (fused) ----------------
__global__ void detect_kernel(const void* __restrict__ xyz, int* __restrict__ flag,
                              int* __restrict__ deg, int N) {
    int idx = blockIdx.x * blockDim.x + threadIdx.x;
    if (idx < N) deg[idx] = 0;
    if (blockIdx.x == 0 && threadIdx.x < 64) {
        const ushort_t* u = (const ushort_t*)xyz;
        unsigned e0 = (u[2 * threadIdx.x] >> 7) & 0xFF;
        unsigned long long bad = __ballot(e0 >= 0x90);
        if (threadIdx.x == 0) *flag = (__popcll(bad) > 2) ? 0 : 1;  // 1=bf16, 0=f32
    }
}

// ---------------- prelude: deg count + s init + weight prep ----------------
// B1 frags [l][ks4][nt8][lane64][8]; B2 frags [l][ks4][nt24][lane64][8];
// WrT f16 [l][col384][KAUG]: k<20 = Wr[l][k][col], k==20 = br[l][col], else 0.
__global__ void prelude_kernel(const void* __restrict__ xyz, const int* __restrict__ nbr,
                               const void* __restrict__ cg_s,
                               const void* __restrict__ W1, const void* __restrict__ W2,
                               const void* __restrict__ Wr, const void* __restrict__ br,
                               float* __restrict__ s_acc, ushort_t* __restrict__ s_hi,
                               ushort_t* __restrict__ s_lo, int* __restrict__ deg,
                               ushort_t* __restrict__ B1hi, ushort_t* __restrict__ B1lo,
                               ushort_t* __restrict__ B2hi, ushort_t* __restrict__ B2lo,
                               _Float16* __restrict__ WrT,
                               int N128, int E, const int* __restrict__ flagp) {
    int isbf = *flagp;
    int idx = blockIdx.x * blockDim.x + threadIdx.x;
    if (idx < E) {
        int i = nbr[2 * idx], j = nbr[2 * idx + 1];
        float dx = ldin(xyz, 3 * j,     isbf) - ldin(xyz, 3 * i,     isbf);
        float dy = ldin(xyz, 3 * j + 1, isbf) - ldin(xyz, 3 * i + 1, isbf);
        float dz = ldin(xyz, 3 * j + 2, isbf) - ldin(xyz, 3 * i + 2, isbf);
        float dist = sqrtf(dx * dx + dy * dy + dz * dz + 3e-15f);
        if (dist < 5.0f) atomicAdd(&deg[i], 1);
    }
    if (idx < N128) {
        float v = ldin(cg_s, idx, isbf);
        s_acc[idx] = v;
        ushort_t hi = f2bf(v);
        s_hi[idx] = hi;
        s_lo[idx] = f2bf(v - bf2f(hi));
    }
    const int NW1 = 3 * 4 * 8 * 64;
    const int NW2 = 3 * 4 * 24 * 64;
    const int NWT = 3 * 384;
    if (idx < NW1) {
        int lane = idx & 63;
        int t = idx >> 6;
        int nt = t % 8; t /= 8;
        int ks = t % 4; int l = t / 4;
        int n = lane & 15, quad = lane >> 4;
        int col = nt * 16 + n;
        size_t base = (size_t)l * 128 * 128;
        size_t fo = (size_t)idx * 8;
        #pragma unroll
        for (int j = 0; j < 8; j++) {
            int k = ks * 32 + quad * 8 + j;
            float v = ldin(W1, base + (size_t)k * 128 + col, isbf);
            ushort_t hi = f2bf(v);
            B1hi[fo + j] = hi;
            B1lo[fo + j] = f2bf(v - bf2f(hi));
        }
    } else if (idx < NW1 + NW2) {
        int i2 = idx - NW1;
        int lane = i2 & 63;
        int t = i2 >> 6;
        int nt = t % 24; t /= 24;
        int ks = t % 4; int l = t / 4;
        int n = lane & 15, quad = lane >> 4;
        int col = nt * 16 + n;
        size_t base = (size_t)l * 128 * 384;
        size_t fo = (size_t)i2 * 8;
        #pragma unroll
        for (int j = 0; j < 8; j++) {
            int k = ks * 32 + quad * 8 + j;
            float v = ldin(W2, base + (size_t)k * 384 + col, isbf);
            ushort_t hi = f2bf(v);
            B2hi[fo + j] = hi;
            B2lo[fo + j] = f2bf(v - bf2f(hi));
        }
    } else if (idx < NW1 + NW2 + NWT) {
        int i2 = idx - NW1 - NW2;
        int l = i2 / 384, col = i2 % 384;
        _Float16* wt = WrT + ((size_t)l * 384 + col) * KAUG;
        #pragma unroll
        for (int k = 0; k < KAUG; k++) {
            float v = 0.f;
            if (k < NRBF) v = ldin(Wr, ((size_t)l * NRBF + k) * 384 + col, isbf);
            else if (k == NRBF) v = ldin(br, (size_t)l * 384 + col, isbf);
            wt[k] = (_Float16)v;
        }
    }
}

// ---------------- scan: rowptr from deg; deg becomes cursor ----------------
__global__ void scan_kernel(int* __restrict__ deg, int* __restrict__ rowptr, int N) {
    __shared__ int part[256];
    int t = threadIdx.x;
    int chunk = (N + 255) / 256;
    int lo = t * chunk, hi = min(lo + chunk, N);
    int s = 0;
    for (int i = lo; i < hi; i++) s += deg[i];
    part[t] = s;
    __syncthreads();
    for (int off = 1; off < 256; off <<= 1) {
        int v = (t >= off) ? part[t - off] : 0;
        __syncthreads();
        if (t >= off) part[t] += v;
        __syncthreads();
    }
    int base = (t == 0) ? 0 : part[t - 1];
    for (int i = lo; i < hi; i++) {
        rowptr[i] = base;
        int d = deg[i];
        deg[i] = base;
        base += d;
    }
    if (t == 0) rowptr[N] = part[255];
}

// ---------------- pack: geometry + CSR scatter (pos-ordered) ----------------
// jlist[pos]=j, upos[pos]=(ux,uy,uz,env), rbfh f16 [pos][KAUG]: k<20 = env*rbf_k,
// k==20 = env (bias row), k>20 = 0.
__global__ void pack_kernel(const void* __restrict__ xyz, const int* __restrict__ nbr,
                            int* __restrict__ cursor, int* __restrict__ jlist,
                            float4* __restrict__ upos, _Float16* __restrict__ rbfh,
                            int E, const int* __restrict__ flagp) {
    int isbf = *flagp;
    int e = blockIdx.x * blockDim.x + threadIdx.x;
    if (e >= E) return;
    int i = nbr[2 * e], j = nbr[2 * e + 1];
    float dx = ldin(xyz, 3 * j,     isbf) - ldin(xyz, 3 * i,     isbf);
    float dy = ldin(xyz, 3 * j + 1, isbf) - ldin(xyz, 3 * i + 1, isbf);
    float dz = ldin(xyz, 3 * j + 2, isbf) - ldin(xyz, 3 * i + 2, isbf);
    float dist = sqrtf(dx * dx + dy * dy + dz * dz + 3e-15f);
    if (!(dist < 5.0f)) return;
    constexpr float PI = 3.14159265358979323846f;
    float ev = 0.5f * (cosf(PI * dist * 0.2f) + 1.0f);
    int pos = atomicAdd(&cursor[i], 1);
    jlist[pos] = j;
    float inv = 1.0f / dist;
    upos[pos] = make_float4(dx * inv, dy * inv, dz * inv, ev);
    constexpr double EM5 = 0.006737946999085467;  // exp(-5)
    constexpr float MU0 = (float)EM5;
    constexpr float DMU = (float)((1.0 - EM5) / 19.0);
    constexpr float BETA = (float)(1.0 / ((0.1 * (1.0 - EM5)) * (0.1 * (1.0 - EM5))));
    float ed = expf(-dist);
    _Float16* rp = rbfh + (size_t)pos * KAUG;
    #pragma unroll
    for (int k = 0; k < NRBF; k++) {
        float dmu = ed - (MU0 + k * DMU);
        rp[k] = (_Float16)(ev * expf(-BETA * dmu * dmu));
    }
    rp[NRBF] = (_Float16)ev;
    #pragma unroll
    for (int k = NRBF + 1; k < KAUG; k++) rp[k] = (_Float16)0.f;
}

// ---------------- MFMA GEMM, 1D swizzled grid for A-locality ----------------
// grid = ceil(M/64) * NTILES, 1D: nt = idx % NTILES (fast), bx = idx / NTILES
// -> consecutive blocks share the same 64 A-rows (L1/L2-hot); B frags are small.
template <int ACT, int OUTMODE, int NTILES>
__global__ __launch_bounds__(256) void mfma_gemm(
    const ushort_t* __restrict__ Ahi, const ushort_t* __restrict__ Alo,
    const ushort_t* __restrict__ Bhi, const ushort_t* __restrict__ Blo,
    const void* __restrict__ bias, size_t biasoff,
    ushort_t* __restrict__ out_hi, ushort_t* __restrict__ out_lo,
    int M, const int* __restrict__ flagp) {
    constexpr int Ncols = NTILES * 16;
    int isbf = *flagp;
    int nt = blockIdx.x % NTILES;
    int bx = blockIdx.x / NTILES;
    int tid = threadIdx.x;
    int wave = tid >> 6, lane = tid & 63;
    int m = lane & 15, quad = lane >> 4;
    int brow = bx * 64 + wave * 16;
    int row = brow + m;
    float4v acc = {};
    short8 zero8 = {};
    #pragma unroll
    for (int ks = 0; ks < 4; ks++) {
        short8 ah = zero8, al = zero8;
        if (row < M) {
            size_t ao = (size_t)row * 128 + ks * 32 + quad * 8;
            ah = *reinterpret_cast<const short8*>(Ahi + ao);
            al = *reinterpret_cast<const short8*>(Alo + ao);
        }
        size_t fo = (((size_t)ks * NTILES + nt) * 64 + lane) * 8;
        short8 bh = *reinterpret_cast<const short8*>(Bhi + fo);
        acc = __builtin_amdgcn_mfma_f32_16x16x32_bf16(ah, bh, acc, 0, 0, 0);
        acc = __builtin_amdgcn_mfma_f32_16x16x32_bf16(al, bh, acc, 0, 0, 0);
        if (!isbf) {
            short8 bl = *reinterpret_cast<const short8*>(Blo + fo);
            acc = __builtin_amdgcn_mfma_f32_16x16x32_bf16(ah, bl, acc, 0, 0, 0);
        }
    }
    int col = nt * 16 + m;
    float bv = ldin(bias, biasoff + col, isbf);
    #pragma unroll
    for (int r = 0; r < 4; r++) {
        int orow = brow + quad * 4 + r;
        if (orow >= M) continue;
        float x = acc[r] + bv;
        if (ACT) x = x / (1.0f + expf(-x));  // silu
        size_t oo = (size_t)orow * Ncols + col;
        ushort_t h = f2bf(x);
        out_hi[oo] = h;
        if (OUTMODE == 0) out_lo[oo] = f2bf(x - bf2f(h));
    }
}

// ---------------- node gather kernel (r4/r8 structure + f16 dot2 w-dot) ----------
// One block per node, 128 threads; thread tt owns features {tt, 128+tt, 256+tt}.
// R4: vectorized loads (G13). WrT cols and rbfh rows are 48B = exactly 3 x
// dwordx4, 16B-aligned by construction -> load as float4 and re-alias the
// registers as half2 lanes for v_dot2. WrT hoist: 99 -> 9 vmem instr; per-edge
// rbf: 11 -> 3 vmem instr. dot2 accumulation order unchanged (the 12th pad
// pair adds exact +0) -> bit-identical results.
template <int L0, int LAST>
__global__ __launch_bounds__(128, 8) void node_kernel(
    const int* __restrict__ rowptr, const int* __restrict__ jlist,
    const float4* __restrict__ upos, const _Float16* __restrict__ rbfh,
    const _Float16* __restrict__ WrT,
    const ushort_t* __restrict__ phi,
    const float* __restrict__ v_old, const ushort_t* __restrict__ vh_old,
    float* __restrict__ s_acc, ushort_t* __restrict__ s_hi, ushort_t* __restrict__ s_lo,
    float* __restrict__ v_new, ushort_t* __restrict__ vh_new,
    void* __restrict__ out, int N, const int* __restrict__ flagp) {
    int isbf = *flagp;
    int tt = threadIdx.x;
    int node = blockIdx.x;

    // hoist this thread's 3 WrT columns: 3 x float4 (48B) each, 9 loads total
    F4H wc0[3], wc1[3], wc2[3];
    {
        const float4v* w0p = (const float4v*)(WrT + (size_t)tt * KAUG);
        const float4v* w1p = (const float4v*)(WrT + (size_t)(tt + 128) * KAUG);
        const float4v* w2p = (const float4v*)(WrT + (size_t)(tt + 256) * KAUG);
        #pragma unroll
        for (int r = 0; r < 3; r++) {
            wc0[r].f = w0p[r]; wc1[r].f = w1p[r]; wc2[r].f = w2p[r];
        }
    }
    int start = __builtin_amdgcn_readfirstlane(rowptr[node]);
    int end   = __builtin_amdgcn_readfirstlane(rowptr[node + 1]);

    float dsv = 0.f, ax = 0.f, ay = 0.f, az = 0.f;
    // scalar j prefetch: j for edge k is loaded during iteration k-1
    int j = (start < end) ? __builtin_amdgcn_readfirstlane(jlist[start]) : 0;
    for (int k = start; k < end; k++) {
        int jn = j;
        if (k + 1 < end) jn = __builtin_amdgcn_readfirstlane(jlist[k + 1]);
        float4 u4 = upos[k];
        const float4v* rp4 = (const float4v*)(rbfh + (size_t)k * KAUG);
        F4H rv0, rv1, rv2;
        rv0.f = rp4[0]; rv1.f = rp4[1]; rv2.f = rp4[2];
        float w0 = 0.f, w1 = 0.f, w2 = 0.f;
        #pragma unroll
        for (int q = 0; q < 4; q++) {
            w0 = dot2(rv0.h[q], wc0[0].h[q], w0);
            w1 = dot2(rv0.h[q], wc1[0].h[q], w1);
            w2 = dot2(rv0.h[q], wc2[0].h[q], w2);
        }
        #pragma unroll
        for (int q = 0; q < 4; q++) {
            w0 = dot2(rv1.h[q], wc0[1].h[q], w0);
            w1 = dot2(rv1.h[q], wc1[1].h[q], w1);
            w2 = dot2(rv1.h[q], wc2[1].h[q], w2);
        }
        #pragma unroll
        for (int q = 0; q < 4; q++) {
            w0 = dot2(rv2.h[q], wc0[2].h[q], w0);
            w1 = dot2(rv2.h[q], wc1[2].h[q], w1);
            w2 = dot2(rv2.h[q], wc2[2].h[q], w2);
        }
        size_t jb = (size_t)j * 384;
        dsv += bf2f(phi[jb + tt]) * w0;
        float gv = bf2f(phi[jb + 128 + tt]) * w1;
        float gu = bf2f(phi[jb + 256 + tt]) * w2;
        if (L0) {
            ax += gu * u4.x; ay += gu * u4.y; az += gu * u4.z;
        } else {
            const ushort_t* vj = &vh_old[jb + (size_t)tt * 3];
            ax += gu * u4.x + gv * bf2f(vj[0]);
            ay += gu * u4.y + gv * bf2f(vj[1]);
            az += gu * u4.z + gv * bf2f(vj[2]);
        }
        j = jn;
    }
    size_t so = (size_t)node * 128 + tt;
    float snew = s_acc[so] + dsv;
    size_t ib = (size_t)node * 384 + (size_t)tt * 3;
    float vx = L0 ? ax : v_old[ib]     + ax;
    float vy = L0 ? ay : v_old[ib + 1] + ay;
    float vz = L0 ? az : v_old[ib + 2] + az;
    if (LAST) {
        stout(out, so, snew, isbf);
        size_t ob = (size_t)N * 128 + ib;
        stout(out, ob,     vx, isbf);
        stout(out, ob + 1, vy, isbf);
        stout(out, ob + 2, vz, isbf);
    } else {
        s_acc[so] = snew;
        ushort_t hi = f2bf(snew);
        s_hi[so] = hi;
        s_lo[so] = f2bf(snew - bf2f(hi));
        v_new[ib] = vx; v_new[ib + 1] = vy; v_new[ib + 2] = vz;
        vh_new[ib]     = f2bf(vx);
        vh_new[ib + 1] = f2bf(vy);
        vh_new[ib + 2] = f2bf(vz);
    }
}

extern "C" void kernel_launch(void* const* d_in, const int* in_sizes, int n_in,
                              void* d_out, int out_size, void* d_ws, size_t ws_size,
                              hipStream_t stream) {
    const int N = in_sizes[0] / 3;
    const int E = in_sizes[1] / 2;
    const void* xyz  = d_in[0];
    const int*  nbr  = (const int*)d_in[1];
    const void* cg_s = d_in[2];
    const void* W1   = d_in[3];
    const void* b1   = d_in[4];
    const void* W2   = d_in[5];
    const void* b2   = d_in[6];
    const void* Wr   = d_in[7];
    const void* br   = d_in[8];

    size_t off = 0;
    auto alloc = [&](size_t bytes) -> char* {
        char* p = (char*)d_ws + off;
        off = (off + bytes + 63) & ~(size_t)63;
        return p;
    };
    int*       flag   = (int*)alloc(64);
    float*     s_acc  = (float*)alloc((size_t)N * 128 * 4);
    float*     vA     = (float*)alloc((size_t)N * 384 * 4);
    float*     vB     = (float*)alloc((size_t)N * 384 * 4);
    int*       rowptr = (int*)alloc((size_t)(N + 1) * 4);
    int*       deg    = (int*)alloc((size_t)N * 4);
    int*       jlist  = (int*)alloc((size_t)E * 4);
    float4*    upos   = (float4*)alloc((size_t)(E + 16) * 16);
    _Float16*  rbfh   = (_Float16*)alloc((size_t)(E + 16) * KAUG * 2);
    _Float16*  WrT    = (_Float16*)alloc((size_t)3 * 384 * KAUG * 2);
    ushort_t*  s_hi   = (ushort_t*)alloc((size_t)N * 128 * 2);
    ushort_t*  s_lo   = (ushort_t*)alloc((size_t)N * 128 * 2);
    ushort_t*  h_hi   = (ushort_t*)alloc((size_t)N * 128 * 2);
    ushort_t*  h_lo   = (ushort_t*)alloc((size_t)N * 128 * 2);
    ushort_t*  phi    = (ushort_t*)alloc((size_t)N * 384 * 2);
    ushort_t*  vhA    = (ushort_t*)alloc((size_t)N * 384 * 2);
    ushort_t*  vhB    = (ushort_t*)alloc((size_t)N * 384 * 2);
    ushort_t*  B1hi   = (ushort_t*)alloc((size_t)3 * 4 * 8 * 64 * 8 * 2);
    ushort_t*  B1lo   = (ushort_t*)alloc((size_t)3 * 4 * 8 * 64 * 8 * 2);
    ushort_t*  B2hi   = (ushort_t*)alloc((size_t)3 * 4 * 24 * 64 * 8 * 2);
    ushort_t*  B2lo   = (ushort_t*)alloc((size_t)3 * 4 * 24 * 64 * 8 * 2);

    detect_kernel<<<(N + 255) / 256, 256, 0, stream>>>(xyz, flag, deg, N);
    const int N128 = N * 128;
    const int pg = (max(E, N128) + 255) / 256;
    prelude_kernel<<<pg, 256, 0, stream>>>(xyz, nbr, cg_s, W1, W2, Wr, br,
                                           s_acc, s_hi, s_lo, deg,
                                           B1hi, B1lo, B2hi, B2lo, WrT,
                                           N128, E, flag);
    scan_kernel<<<1, 256, 0, stream>>>(deg, rowptr, N);
    pack_kernel<<<(E + 255) / 256, 256, 0, stream>>>(xyz, nbr, deg, jlist, upos,
                                                     rbfh, E, flag);

    const int gx = (N + 63) / 64;
    for (int l = 0; l < 3; l++) {
        mfma_gemm<1, 0, 8><<<gx * 8, 256, 0, stream>>>(
            s_hi, s_lo,
            B1hi + (size_t)l * 4 * 8 * 64 * 8, B1lo + (size_t)l * 4 * 8 * 64 * 8,
            b1, (size_t)l * 128, h_hi, h_lo, N, flag);
        mfma_gemm<0, 1, 24><<<gx * 24, 256, 0, stream>>>(
            h_hi, h_lo,
            B2hi + (size_t)l * 4 * 24 * 64 * 8, B2lo + (size_t)l * 4 * 24 * 64 * 8,
            b2, (size_t)l * 384, phi, (ushort_t*)nullptr, N, flag);
        const _Float16* wrt = WrT + (size_t)l * 384 * KAUG;
        if (l == 0) {
            node_kernel<1, 0><<<N, 128, 0, stream>>>(
                rowptr, jlist, upos, rbfh, wrt, phi,
                vA, vhA, s_acc, s_hi, s_lo, vA, vhA, d_out, N, flag);
        } else if (l == 1) {
            node_kernel<0, 0><<<N, 128, 0, stream>>>(
                rowptr, jlist, upos, rbfh, wrt, phi,
                vA, vhA, s_acc, s_hi, s_lo, vB, vhB, d_out, N, flag);
        } else {
            node_kernel<0, 1><<<N, 128, 0, stream>>>(
                rowptr, jlist, upos, rbfh, wrt, phi,
                vB, vhB, s_acc, s_hi, s_lo, vB, vhB, d_out, N, flag);
        }
    }
}